// Round 4
// baseline (1710.313 us; speedup 1.0000x reference)
//
#include <hip/hip_runtime.h>
#include <cstdint>
#include <cstddef>

// MultiHeadAttention: B=2, N=2048, EMB=2048, H=8, D=256.  fp32 I/O.
// Accuracy strategy: logits (QK^T) must be fp32-grade (softmax on unscaled
// logits with std~16 is near-one-hot; bf16 logit jitter was 1.6x over
// threshold in R3).  Q,K computed with split-bf16 3-pass MFMA end to end and
// stored fp32.  V / P / attn-out / proj stay bf16 (contribute ~1e-3 absmax).
// ws (96 MiB, proven safe): qf32 32M | kf32 32M | vT 16M | attn 16M ;
// wprojT aliases qf32 after attention.

typedef __bf16 bf16x8 __attribute__((ext_vector_type(8)));
typedef __bf16 bf16x2 __attribute__((ext_vector_type(2)));
typedef float f32x4 __attribute__((ext_vector_type(4)));

#define SCALE_INV 0.022097086912079608f  // 1/sqrt(2048)

__device__ inline void split8(const float4 v0, const float4 v1, bf16x8& hi,
                              bf16x8& lo) {
  float a[8] = {v0.x, v0.y, v0.z, v0.w, v1.x, v1.y, v1.z, v1.w};
  bf16x8 h, l;
#pragma unroll
  for (int i = 0; i < 8; i++) {
    __bf16 hh = (__bf16)a[i];
    h[i] = hh;
    l[i] = (__bf16)(a[i] - (float)hh);
  }
  hi = h;
  lo = l;
}

// out[c][r] = (bf16) in[r][c]
__global__ __launch_bounds__(256) void transpose_cvt_k(
    const float* __restrict__ in, __bf16* __restrict__ out, int R, int C) {
  __shared__ float tile[32][33];
  const int tx = threadIdx.x & 31;
  const int ty = threadIdx.x >> 5;
  const int c0 = blockIdx.x * 32;
  const int r0 = blockIdx.y * 32;
#pragma unroll
  for (int i = 0; i < 32; i += 8)
    tile[ty + i][tx] = in[(size_t)(r0 + ty + i) * C + (c0 + tx)];
  __syncthreads();
#pragma unroll
  for (int i = 0; i < 32; i += 8)
    out[(size_t)(c0 + ty + i) * R + (r0 + tx)] = (__bf16)tile[tx][ty + i];
}

// QKV GEMM, split-bf16 3-pass.  A = X fp32 [4096][2048] row-major.
// B = W fp32 [2048][6144] row-major (transposed during LDS staging).
// Scatter: col = h*768 + d*3 + c -> q fp32, k fp32, vT bf16.
__global__ __launch_bounds__(256) void gemm_qkv_split_k(
    const float* __restrict__ X, const float* __restrict__ W,
    const float* __restrict__ bias, float* __restrict__ qf,
    float* __restrict__ kf, __bf16* __restrict__ vT) {
  __shared__ __bf16 Ah[128 * 40], Al[128 * 40];
  __shared__ __bf16 Bh[128 * 40], Bl[128 * 40];
  const int tid = threadIdx.x, lane = tid & 63, wave = tid >> 6;
  const int l16 = lane & 15, quad = lane >> 4;
  const int wm = (wave >> 1) * 64, wn = (wave & 1) * 64;
  const int m0 = blockIdx.y * 128, n0 = blockIdx.x * 128;
  const int r0 = tid >> 2, kc0 = (tid & 3) * 8;
  const int bn = tid & 31;        // B-staging: base n (coalesced)
  const int bk = (tid >> 5) * 2;  // B-staging: even k in [0,16)

  f32x4 zero4 = {0.f, 0.f, 0.f, 0.f};
  f32x4 acc[4][4];
#pragma unroll
  for (int i = 0; i < 4; i++)
#pragma unroll
    for (int j = 0; j < 4; j++) acc[i][j] = zero4;

  const float* Arow0 = X + (size_t)(m0 + r0) * 2048 + kc0;
  const float* Arow1 = Arow0 + (size_t)64 * 2048;

  for (int k0 = 0; k0 < 2048; k0 += 32) {
    float4 a00 = *(const float4*)(Arow0 + k0);
    float4 a01 = *(const float4*)(Arow0 + k0 + 4);
    float4 a10 = *(const float4*)(Arow1 + k0);
    float4 a11 = *(const float4*)(Arow1 + k0 + 4);
    float wv[2][4][2];
#pragma unroll
    for (int p = 0; p < 2; p++) {
      const int kk = k0 + p * 16 + bk;
#pragma unroll
      for (int i = 0; i < 4; i++) {
        const int nn = n0 + bn + 32 * i;
        wv[p][i][0] = W[(size_t)kk * 6144 + nn];
        wv[p][i][1] = W[(size_t)(kk + 1) * 6144 + nn];
      }
    }
    bf16x8 ah0, al0, ah1, al1;
    split8(a00, a01, ah0, al0);
    split8(a10, a11, ah1, al1);
    __syncthreads();
    *(bf16x8*)&Ah[r0 * 40 + kc0] = ah0;
    *(bf16x8*)&Al[r0 * 40 + kc0] = al0;
    *(bf16x8*)&Ah[(r0 + 64) * 40 + kc0] = ah1;
    *(bf16x8*)&Al[(r0 + 64) * 40 + kc0] = al1;
#pragma unroll
    for (int p = 0; p < 2; p++) {
      const int kk = p * 16 + bk;
#pragma unroll
      for (int i = 0; i < 4; i++) {
        const int nn = bn + 32 * i;
        const float a = wv[p][i][0], b = wv[p][i][1];
        __bf16 h0 = (__bf16)a, h1 = (__bf16)b;
        bf16x2 h = {h0, h1};
        bf16x2 l = {(__bf16)(a - (float)h0), (__bf16)(b - (float)h1)};
        *(bf16x2*)&Bh[nn * 40 + kk] = h;
        *(bf16x2*)&Bl[nn * 40 + kk] = l;
      }
    }
    __syncthreads();
    bf16x8 fah[4], fal[4], fbh[4], fbl[4];
#pragma unroll
    for (int i = 0; i < 4; i++) {
      fah[i] = *(const bf16x8*)&Ah[(wm + i * 16 + l16) * 40 + quad * 8];
      fal[i] = *(const bf16x8*)&Al[(wm + i * 16 + l16) * 40 + quad * 8];
    }
#pragma unroll
    for (int j = 0; j < 4; j++) {
      fbh[j] = *(const bf16x8*)&Bh[(wn + j * 16 + l16) * 40 + quad * 8];
      fbl[j] = *(const bf16x8*)&Bl[(wn + j * 16 + l16) * 40 + quad * 8];
    }
#pragma unroll
    for (int i = 0; i < 4; i++)
#pragma unroll
      for (int j = 0; j < 4; j++) {
        acc[i][j] = __builtin_amdgcn_mfma_f32_16x16x32_bf16(fah[i], fbh[j],
                                                            acc[i][j], 0, 0, 0);
        acc[i][j] = __builtin_amdgcn_mfma_f32_16x16x32_bf16(fah[i], fbl[j],
                                                            acc[i][j], 0, 0, 0);
        acc[i][j] = __builtin_amdgcn_mfma_f32_16x16x32_bf16(fal[i], fbh[j],
                                                            acc[i][j], 0, 0, 0);
      }
  }

#pragma unroll
  for (int i = 0; i < 4; i++) {
#pragma unroll
    for (int j = 0; j < 4; j++) {
      const int col = n0 + wn + j * 16 + l16;
      const float bv = bias[col];
      const int h = col / 768;
      const int rr = col - h * 768;
      const int d = rr / 3;
      const int c = rr - d * 3;
#pragma unroll
      for (int r = 0; r < 4; r++) {
        const int row = m0 + wm + i * 16 + quad * 4 + r;
        const float v = acc[i][j][r] + bv;
        const int b = row >> 11;
        const int nn = row & 2047;
        const int bh = b * 8 + h;
        if (c == 0)
          qf[((size_t)bh * 2048 + nn) * 256 + d] = v;
        else if (c == 1)
          kf[((size_t)bh * 2048 + nn) * 256 + d] = v;
        else
          vT[((size_t)bh * 256 + d) * 2048 + nn] = (__bf16)v;
      }
    }
  }
}

// Flash attention, fp32 Q/K with split-bf16 3-pass QK^T.
__global__ __launch_bounds__(256) void attn_fwd_k(
    const float* __restrict__ Q,    // [16][2048][256] fp32
    const float* __restrict__ K,    // [16][2048][256] fp32
    const __bf16* __restrict__ Vt,  // [16][256][2048] bf16
    __bf16* __restrict__ out) {     // [2][2048][2048] (b, n, h*256+d)
  const int qblk = blockIdx.x;
  const int bh = blockIdx.y;
  const int bb = bh >> 3, hh = bh & 7;
  const int tid = threadIdx.x, lane = tid & 63, wave = tid >> 6;
  const int l16 = lane & 15, quad = lane >> 4;

  const float* qp = Q + (size_t)bh * 2048 * 256;
  const float* kp = K + (size_t)bh * 2048 * 256;
  const __bf16* vp = Vt + (size_t)bh * 256 * 2048;

  const int qrow = qblk * 64 + wave * 16;

  bf16x8 qh[8], ql[8];
#pragma unroll
  for (int t = 0; t < 8; t++) {
    const float* qr = &qp[(size_t)(qrow + l16) * 256 + t * 32 + quad * 8];
    split8(*(const float4*)qr, *(const float4*)(qr + 4), qh[t], ql[t]);
  }

  f32x4 zero4 = {0.f, 0.f, 0.f, 0.f};
  f32x4 o[16];
#pragma unroll
  for (int dt = 0; dt < 16; dt++) o[dt] = zero4;
  float mrow[4], lrow[4];
#pragma unroll
  for (int r = 0; r < 4; r++) {
    mrow[r] = -3.0e38f;
    lrow[r] = 0.f;
  }

  __shared__ __bf16 Plds[4][16 * 72];

  for (int kv0 = 0; kv0 < 2048; kv0 += 64) {
    f32x4 s[4];
#pragma unroll
    for (int j = 0; j < 4; j++) s[j] = zero4;
#pragma unroll
    for (int j = 0; j < 4; j++) {
#pragma unroll
      for (int t = 0; t < 8; t++) {
        const float* kr =
            &kp[(size_t)(kv0 + j * 16 + l16) * 256 + t * 32 + quad * 8];
        bf16x8 kh, kl;
        split8(*(const float4*)kr, *(const float4*)(kr + 4), kh, kl);
        s[j] = __builtin_amdgcn_mfma_f32_16x16x32_bf16(qh[t], kh, s[j], 0, 0, 0);
        s[j] = __builtin_amdgcn_mfma_f32_16x16x32_bf16(qh[t], kl, s[j], 0, 0, 0);
        s[j] = __builtin_amdgcn_mfma_f32_16x16x32_bf16(ql[t], kh, s[j], 0, 0, 0);
      }
    }
    float mnew[4], alpha[4], psum[4];
#pragma unroll
    for (int r = 0; r < 4; r++) {
      float mx = fmaxf(fmaxf(s[0][r], s[1][r]), fmaxf(s[2][r], s[3][r]));
#pragma unroll
      for (int off = 1; off < 16; off <<= 1)
        mx = fmaxf(mx, __shfl_xor(mx, off, 16));
      mnew[r] = fmaxf(mrow[r], mx);
      alpha[r] = __expf(mrow[r] - mnew[r]);
      psum[r] = 0.f;
    }
#pragma unroll
    for (int j = 0; j < 4; j++)
#pragma unroll
      for (int r = 0; r < 4; r++) {
        float p = __expf(s[j][r] - mnew[r]);
        s[j][r] = p;
        psum[r] += p;
      }
#pragma unroll
    for (int r = 0; r < 4; r++) {
#pragma unroll
      for (int off = 1; off < 16; off <<= 1)
        psum[r] += __shfl_xor(psum[r], off, 16);
      lrow[r] = lrow[r] * alpha[r] + psum[r];
      mrow[r] = mnew[r];
    }
#pragma unroll
    for (int dt = 0; dt < 16; dt++) {
      o[dt][0] *= alpha[0];
      o[dt][1] *= alpha[1];
      o[dt][2] *= alpha[2];
      o[dt][3] *= alpha[3];
    }
    __syncthreads();
#pragma unroll
    for (int j = 0; j < 4; j++)
#pragma unroll
      for (int r = 0; r < 4; r++)
        Plds[wave][(quad * 4 + r) * 72 + j * 16 + l16] = (__bf16)s[j][r];
    __syncthreads();
    bf16x8 pa0 = *(const bf16x8*)&Plds[wave][l16 * 72 + quad * 8];
    bf16x8 pa1 = *(const bf16x8*)&Plds[wave][l16 * 72 + 32 + quad * 8];
#pragma unroll
    for (int dt = 0; dt < 16; dt++) {
      bf16x8 vf0 =
          *(const bf16x8*)&vp[(size_t)(dt * 16 + l16) * 2048 + kv0 + quad * 8];
      bf16x8 vf1 = *(const bf16x8*)&vp[(size_t)(dt * 16 + l16) * 2048 + kv0 +
                                       32 + quad * 8];
      o[dt] = __builtin_amdgcn_mfma_f32_16x16x32_bf16(pa0, vf0, o[dt], 0, 0, 0);
      o[dt] = __builtin_amdgcn_mfma_f32_16x16x32_bf16(pa1, vf1, o[dt], 0, 0, 0);
    }
  }

#pragma unroll
  for (int r = 0; r < 4; r++) {
    const float inv = SCALE_INV / lrow[r];
    const int n = qrow + quad * 4 + r;
    const size_t base = ((size_t)bb * 2048 + n) * 2048 + hh * 256;
#pragma unroll
    for (int dt = 0; dt < 16; dt++)
      out[base + dt * 16 + l16] = (__bf16)(o[dt][r] * inv);
  }
}

// Plain bf16 GEMM, C = A[M][K] * Bt[N][K]^T + bias, fp32 store.
__global__ __launch_bounds__(256) void gemm_bt_k(
    const __bf16* __restrict__ A, const __bf16* __restrict__ Bt,
    const float* __restrict__ bias, int M, int Ncols, int K,
    float* __restrict__ outF) {
  __shared__ __bf16 As[128 * 40];
  __shared__ __bf16 Bs[128 * 40];
  const int tid = threadIdx.x, lane = tid & 63, wave = tid >> 6;
  const int l16 = lane & 15, quad = lane >> 4;
  const int wm = (wave >> 1) * 64, wn = (wave & 1) * 64;
  const int m0 = blockIdx.y * 128, n0 = blockIdx.x * 128;
  const int r0 = tid >> 2, kc0 = (tid & 3) * 8;

  f32x4 zero4 = {0.f, 0.f, 0.f, 0.f};
  f32x4 acc[4][4];
#pragma unroll
  for (int i = 0; i < 4; i++)
#pragma unroll
    for (int j = 0; j < 4; j++) acc[i][j] = zero4;

  const __bf16* Aptr = A + (size_t)(m0 + r0) * K + kc0;
  const __bf16* Bptr = Bt + (size_t)(n0 + r0) * K + kc0;
  const size_t rowstep = (size_t)64 * K;

  for (int k0 = 0; k0 < K; k0 += 32) {
    uint4 a0 = *(const uint4*)(Aptr + k0);
    uint4 a1 = *(const uint4*)(Aptr + rowstep + k0);
    uint4 b0 = *(const uint4*)(Bptr + k0);
    uint4 b1 = *(const uint4*)(Bptr + rowstep + k0);
    __syncthreads();
    *(uint4*)&As[r0 * 40 + kc0] = a0;
    *(uint4*)&As[(r0 + 64) * 40 + kc0] = a1;
    *(uint4*)&Bs[r0 * 40 + kc0] = b0;
    *(uint4*)&Bs[(r0 + 64) * 40 + kc0] = b1;
    __syncthreads();
    bf16x8 af[4], bfv[4];
#pragma unroll
    for (int i = 0; i < 4; i++)
      af[i] = *(const bf16x8*)&As[(wm + i * 16 + l16) * 40 + quad * 8];
#pragma unroll
    for (int j = 0; j < 4; j++)
      bfv[j] = *(const bf16x8*)&Bs[(wn + j * 16 + l16) * 40 + quad * 8];
#pragma unroll
    for (int i = 0; i < 4; i++)
#pragma unroll
      for (int j = 0; j < 4; j++)
        acc[i][j] = __builtin_amdgcn_mfma_f32_16x16x32_bf16(af[i], bfv[j],
                                                            acc[i][j], 0, 0, 0);
  }

#pragma unroll
  for (int i = 0; i < 4; i++)
#pragma unroll
    for (int j = 0; j < 4; j++) {
      const int col = n0 + wn + j * 16 + l16;
      const float bv = bias[col];
#pragma unroll
      for (int r = 0; r < 4; r++) {
        const int row = m0 + wm + i * 16 + quad * 4 + r;
        outF[(size_t)row * Ncols + col] = acc[i][j][r] + bv;
      }
    }
}

extern "C" void kernel_launch(void* const* d_in, const int* in_sizes, int n_in,
                              void* d_out, int out_size, void* d_ws,
                              size_t ws_size, hipStream_t stream) {
  const float* x = (const float*)d_in[0];       // [2,2048,2048]
  const float* w_qkv = (const float*)d_in[1];   // [2048,6144]
  const float* b_qkv = (const float*)d_in[2];   // [6144]
  const float* w_proj = (const float*)d_in[3];  // [2048,2048]
  const float* b_proj = (const float*)d_in[4];  // [2048]
  float* out = (float*)d_out;                   // [2,2048,2048] fp32

  float* qf = (float*)d_ws;                   // [16][2048][256] f32, 32 MiB
  float* kf = qf + (size_t)16 * 2048 * 256;   // 32 MiB
  __bf16* vT = (__bf16*)(kf + (size_t)16 * 2048 * 256);  // 16 MiB
  __bf16* attn = vT + (size_t)16 * 256 * 2048;           // 16 MiB
  __bf16* wprojT = (__bf16*)qf;  // aliases q region AFTER attention

  gemm_qkv_split_k<<<dim3(48, 32), 256, 0, stream>>>(x, w_qkv, b_qkv, qf, kf,
                                                     vT);
  attn_fwd_k<<<dim3(32, 16), 256, 0, stream>>>(qf, kf, vT, attn);
  transpose_cvt_k<<<dim3(64, 64), 256, 0, stream>>>(w_proj, wprojT, 2048, 2048);
  gemm_bt_k<<<dim3(16, 32), 256, 0, stream>>>(attn, wprojT, b_proj, 4096, 2048,
                                              2048, out);
}

// Round 5
// 1566.761 us; speedup vs baseline: 1.0916x; 1.0916x over previous
//
#include <hip/hip_runtime.h>
#include <cstdint>
#include <cstddef>

// MultiHeadAttention: B=2, N=2048, EMB=2048, H=8, D=256.  fp32 I/O.
// R4 passed (absmax 4.9e-4) at 1710 us; attn_fwd_k = 70% of time, latency-bound
// (MfmaUtil 4.7%, VALUBusy 11.7%, occ 11.8%).  R5: (1) QKV GEMM emits Q,K as
// hi/lo bf16 pairs (split once in epilogue, not per-use in attention inner
// loop -- identical numerics, kills ~770 VALU ops/kv-iter); (2) remove the two
// per-iter __syncthreads around the per-wave P LDS staging (no cross-wave
// sharing -> no barrier needed).
// ws (96 MiB): qh 16 | ql 16 | kh 16 | kl 16 | vT 16 | attn 16 ;
// wprojT aliases qh after attention.

typedef __bf16 bf16x8 __attribute__((ext_vector_type(8)));
typedef __bf16 bf16x2 __attribute__((ext_vector_type(2)));
typedef float f32x4 __attribute__((ext_vector_type(4)));

#define SCALE_INV 0.022097086912079608f  // 1/sqrt(2048)

__device__ inline void split8(const float4 v0, const float4 v1, bf16x8& hi,
                              bf16x8& lo) {
  float a[8] = {v0.x, v0.y, v0.z, v0.w, v1.x, v1.y, v1.z, v1.w};
  bf16x8 h, l;
#pragma unroll
  for (int i = 0; i < 8; i++) {
    __bf16 hh = (__bf16)a[i];
    h[i] = hh;
    l[i] = (__bf16)(a[i] - (float)hh);
  }
  hi = h;
  lo = l;
}

// out[c][r] = (bf16) in[r][c]
__global__ __launch_bounds__(256) void transpose_cvt_k(
    const float* __restrict__ in, __bf16* __restrict__ out, int R, int C) {
  __shared__ float tile[32][33];
  const int tx = threadIdx.x & 31;
  const int ty = threadIdx.x >> 5;
  const int c0 = blockIdx.x * 32;
  const int r0 = blockIdx.y * 32;
#pragma unroll
  for (int i = 0; i < 32; i += 8)
    tile[ty + i][tx] = in[(size_t)(r0 + ty + i) * C + (c0 + tx)];
  __syncthreads();
#pragma unroll
  for (int i = 0; i < 32; i += 8)
    out[(size_t)(c0 + ty + i) * R + (r0 + tx)] = (__bf16)tile[tx][ty + i];
}

// QKV GEMM, split-bf16 3-pass.  A = X fp32 [4096][2048] row-major.
// B = W fp32 [2048][6144] row-major (transposed during LDS staging).
// Scatter: col = h*768 + d*3 + c -> qh/ql, kh/kl (bf16 hi/lo pairs), vT bf16.
__global__ __launch_bounds__(256) void gemm_qkv_split_k(
    const float* __restrict__ X, const float* __restrict__ W,
    const float* __restrict__ bias, __bf16* __restrict__ qh_,
    __bf16* __restrict__ ql_, __bf16* __restrict__ kh_,
    __bf16* __restrict__ kl_, __bf16* __restrict__ vT) {
  __shared__ __bf16 Ah[128 * 40], Al[128 * 40];
  __shared__ __bf16 Bh[128 * 40], Bl[128 * 40];
  const int tid = threadIdx.x, lane = tid & 63, wave = tid >> 6;
  const int l16 = lane & 15, quad = lane >> 4;
  const int wm = (wave >> 1) * 64, wn = (wave & 1) * 64;
  const int m0 = blockIdx.y * 128, n0 = blockIdx.x * 128;
  const int r0 = tid >> 2, kc0 = (tid & 3) * 8;
  const int bn = tid & 31;        // B-staging: base n (coalesced)
  const int bk = (tid >> 5) * 2;  // B-staging: even k in [0,16)

  f32x4 zero4 = {0.f, 0.f, 0.f, 0.f};
  f32x4 acc[4][4];
#pragma unroll
  for (int i = 0; i < 4; i++)
#pragma unroll
    for (int j = 0; j < 4; j++) acc[i][j] = zero4;

  const float* Arow0 = X + (size_t)(m0 + r0) * 2048 + kc0;
  const float* Arow1 = Arow0 + (size_t)64 * 2048;

  for (int k0 = 0; k0 < 2048; k0 += 32) {
    float4 a00 = *(const float4*)(Arow0 + k0);
    float4 a01 = *(const float4*)(Arow0 + k0 + 4);
    float4 a10 = *(const float4*)(Arow1 + k0);
    float4 a11 = *(const float4*)(Arow1 + k0 + 4);
    float wv[2][4][2];
#pragma unroll
    for (int p = 0; p < 2; p++) {
      const int kk = k0 + p * 16 + bk;
#pragma unroll
      for (int i = 0; i < 4; i++) {
        const int nn = n0 + bn + 32 * i;
        wv[p][i][0] = W[(size_t)kk * 6144 + nn];
        wv[p][i][1] = W[(size_t)(kk + 1) * 6144 + nn];
      }
    }
    bf16x8 ah0, al0, ah1, al1;
    split8(a00, a01, ah0, al0);
    split8(a10, a11, ah1, al1);
    __syncthreads();
    *(bf16x8*)&Ah[r0 * 40 + kc0] = ah0;
    *(bf16x8*)&Al[r0 * 40 + kc0] = al0;
    *(bf16x8*)&Ah[(r0 + 64) * 40 + kc0] = ah1;
    *(bf16x8*)&Al[(r0 + 64) * 40 + kc0] = al1;
#pragma unroll
    for (int p = 0; p < 2; p++) {
      const int kk = p * 16 + bk;
#pragma unroll
      for (int i = 0; i < 4; i++) {
        const int nn = bn + 32 * i;
        const float a = wv[p][i][0], b = wv[p][i][1];
        __bf16 h0 = (__bf16)a, h1 = (__bf16)b;
        bf16x2 h = {h0, h1};
        bf16x2 l = {(__bf16)(a - (float)h0), (__bf16)(b - (float)h1)};
        *(bf16x2*)&Bh[nn * 40 + kk] = h;
        *(bf16x2*)&Bl[nn * 40 + kk] = l;
      }
    }
    __syncthreads();
    bf16x8 fah[4], fal[4], fbh[4], fbl[4];
#pragma unroll
    for (int i = 0; i < 4; i++) {
      fah[i] = *(const bf16x8*)&Ah[(wm + i * 16 + l16) * 40 + quad * 8];
      fal[i] = *(const bf16x8*)&Al[(wm + i * 16 + l16) * 40 + quad * 8];
    }
#pragma unroll
    for (int j = 0; j < 4; j++) {
      fbh[j] = *(const bf16x8*)&Bh[(wn + j * 16 + l16) * 40 + quad * 8];
      fbl[j] = *(const bf16x8*)&Bl[(wn + j * 16 + l16) * 40 + quad * 8];
    }
#pragma unroll
    for (int i = 0; i < 4; i++)
#pragma unroll
      for (int j = 0; j < 4; j++) {
        acc[i][j] = __builtin_amdgcn_mfma_f32_16x16x32_bf16(fah[i], fbh[j],
                                                            acc[i][j], 0, 0, 0);
        acc[i][j] = __builtin_amdgcn_mfma_f32_16x16x32_bf16(fah[i], fbl[j],
                                                            acc[i][j], 0, 0, 0);
        acc[i][j] = __builtin_amdgcn_mfma_f32_16x16x32_bf16(fal[i], fbh[j],
                                                            acc[i][j], 0, 0, 0);
      }
  }

#pragma unroll
  for (int i = 0; i < 4; i++) {
#pragma unroll
    for (int j = 0; j < 4; j++) {
      const int col = n0 + wn + j * 16 + l16;
      const float bv = bias[col];
      const int h = col / 768;
      const int rr = col - h * 768;
      const int d = rr / 3;
      const int c = rr - d * 3;
#pragma unroll
      for (int r = 0; r < 4; r++) {
        const int row = m0 + wm + i * 16 + quad * 4 + r;
        const float v = acc[i][j][r] + bv;
        const int b = row >> 11;
        const int nn = row & 2047;
        const int bh = b * 8 + h;
        const size_t idx = ((size_t)bh * 2048 + nn) * 256 + d;
        if (c == 0) {
          __bf16 hi = (__bf16)v;
          qh_[idx] = hi;
          ql_[idx] = (__bf16)(v - (float)hi);
        } else if (c == 1) {
          __bf16 hi = (__bf16)v;
          kh_[idx] = hi;
          kl_[idx] = (__bf16)(v - (float)hi);
        } else {
          vT[((size_t)bh * 256 + d) * 2048 + nn] = (__bf16)v;
        }
      }
    }
  }
}

// Flash attention, Q/K as prestored hi/lo bf16 pairs; 3-pass QK^T.
__global__ __launch_bounds__(256) void attn_fwd_k(
    const __bf16* __restrict__ Qh,  // [16][2048][256]
    const __bf16* __restrict__ Ql,
    const __bf16* __restrict__ Kh,
    const __bf16* __restrict__ Kl,
    const __bf16* __restrict__ Vt,  // [16][256][2048]
    __bf16* __restrict__ out) {     // [2][2048][2048] (b, n, h*256+d)
  const int qblk = blockIdx.x;
  const int bh = blockIdx.y;
  const int bb = bh >> 3, hh = bh & 7;
  const int tid = threadIdx.x, lane = tid & 63, wave = tid >> 6;
  const int l16 = lane & 15, quad = lane >> 4;

  const size_t hqk = (size_t)bh * 2048 * 256;
  const __bf16* qhp = Qh + hqk;
  const __bf16* qlp = Ql + hqk;
  const __bf16* khp = Kh + hqk;
  const __bf16* klp = Kl + hqk;
  const __bf16* vp = Vt + (size_t)bh * 256 * 2048;

  const int qrow = qblk * 64 + wave * 16;

  bf16x8 qhf[8], qlf[8];
#pragma unroll
  for (int t = 0; t < 8; t++) {
    const size_t off = (size_t)(qrow + l16) * 256 + t * 32 + quad * 8;
    qhf[t] = *(const bf16x8*)&qhp[off];
    qlf[t] = *(const bf16x8*)&qlp[off];
  }

  f32x4 zero4 = {0.f, 0.f, 0.f, 0.f};
  f32x4 o[16];
#pragma unroll
  for (int dt = 0; dt < 16; dt++) o[dt] = zero4;
  float mrow[4], lrow[4];
#pragma unroll
  for (int r = 0; r < 4; r++) {
    mrow[r] = -3.0e38f;
    lrow[r] = 0.f;
  }

  __shared__ __bf16 Plds[4][16 * 72];  // per-wave; no cross-wave sharing

  for (int kv0 = 0; kv0 < 2048; kv0 += 64) {
    f32x4 s[4];
#pragma unroll
    for (int j = 0; j < 4; j++) s[j] = zero4;
#pragma unroll
    for (int j = 0; j < 4; j++) {
#pragma unroll
      for (int t = 0; t < 8; t++) {
        const size_t off =
            (size_t)(kv0 + j * 16 + l16) * 256 + t * 32 + quad * 8;
        bf16x8 khf = *(const bf16x8*)&khp[off];
        bf16x8 klf = *(const bf16x8*)&klp[off];
        s[j] =
            __builtin_amdgcn_mfma_f32_16x16x32_bf16(qhf[t], khf, s[j], 0, 0, 0);
        s[j] =
            __builtin_amdgcn_mfma_f32_16x16x32_bf16(qhf[t], klf, s[j], 0, 0, 0);
        s[j] =
            __builtin_amdgcn_mfma_f32_16x16x32_bf16(qlf[t], khf, s[j], 0, 0, 0);
      }
    }
    float mnew[4], alpha[4], psum[4];
#pragma unroll
    for (int r = 0; r < 4; r++) {
      float mx = fmaxf(fmaxf(s[0][r], s[1][r]), fmaxf(s[2][r], s[3][r]));
#pragma unroll
      for (int off = 1; off < 16; off <<= 1)
        mx = fmaxf(mx, __shfl_xor(mx, off, 16));
      mnew[r] = fmaxf(mrow[r], mx);
      alpha[r] = __expf(mrow[r] - mnew[r]);
      psum[r] = 0.f;
    }
#pragma unroll
    for (int j = 0; j < 4; j++)
#pragma unroll
      for (int r = 0; r < 4; r++) {
        float p = __expf(s[j][r] - mnew[r]);
        s[j][r] = p;
        psum[r] += p;
      }
#pragma unroll
    for (int r = 0; r < 4; r++) {
#pragma unroll
      for (int off = 1; off < 16; off <<= 1)
        psum[r] += __shfl_xor(psum[r], off, 16);
      lrow[r] = lrow[r] * alpha[r] + psum[r];
      mrow[r] = mnew[r];
    }
#pragma unroll
    for (int dt = 0; dt < 16; dt++) {
      o[dt][0] *= alpha[0];
      o[dt][1] *= alpha[1];
      o[dt][2] *= alpha[2];
      o[dt][3] *= alpha[3];
    }
    // P: C-layout -> per-wave LDS -> A-operand layout (no barrier needed:
    // wave-private buffer, compiler inserts lgkmcnt waits)
#pragma unroll
    for (int j = 0; j < 4; j++)
#pragma unroll
      for (int r = 0; r < 4; r++)
        Plds[wave][(quad * 4 + r) * 72 + j * 16 + l16] = (__bf16)s[j][r];
    bf16x8 pa0 = *(const bf16x8*)&Plds[wave][l16 * 72 + quad * 8];
    bf16x8 pa1 = *(const bf16x8*)&Plds[wave][l16 * 72 + 32 + quad * 8];
#pragma unroll
    for (int dt = 0; dt < 16; dt++) {
      bf16x8 vf0 =
          *(const bf16x8*)&vp[(size_t)(dt * 16 + l16) * 2048 + kv0 + quad * 8];
      bf16x8 vf1 = *(const bf16x8*)&vp[(size_t)(dt * 16 + l16) * 2048 + kv0 +
                                       32 + quad * 8];
      o[dt] = __builtin_amdgcn_mfma_f32_16x16x32_bf16(pa0, vf0, o[dt], 0, 0, 0);
      o[dt] = __builtin_amdgcn_mfma_f32_16x16x32_bf16(pa1, vf1, o[dt], 0, 0, 0);
    }
  }

#pragma unroll
  for (int r = 0; r < 4; r++) {
    const float inv = SCALE_INV / lrow[r];
    const int n = qrow + quad * 4 + r;
    const size_t base = ((size_t)bb * 2048 + n) * 2048 + hh * 256;
#pragma unroll
    for (int dt = 0; dt < 16; dt++)
      out[base + dt * 16 + l16] = (__bf16)(o[dt][r] * inv);
  }
}

// Plain bf16 GEMM, C = A[M][K] * Bt[N][K]^T + bias, fp32 store.
__global__ __launch_bounds__(256) void gemm_bt_k(
    const __bf16* __restrict__ A, const __bf16* __restrict__ Bt,
    const float* __restrict__ bias, int M, int Ncols, int K,
    float* __restrict__ outF) {
  __shared__ __bf16 As[128 * 40];
  __shared__ __bf16 Bs[128 * 40];
  const int tid = threadIdx.x, lane = tid & 63, wave = tid >> 6;
  const int l16 = lane & 15, quad = lane >> 4;
  const int wm = (wave >> 1) * 64, wn = (wave & 1) * 64;
  const int m0 = blockIdx.y * 128, n0 = blockIdx.x * 128;
  const int r0 = tid >> 2, kc0 = (tid & 3) * 8;

  f32x4 zero4 = {0.f, 0.f, 0.f, 0.f};
  f32x4 acc[4][4];
#pragma unroll
  for (int i = 0; i < 4; i++)
#pragma unroll
    for (int j = 0; j < 4; j++) acc[i][j] = zero4;

  const __bf16* Aptr = A + (size_t)(m0 + r0) * K + kc0;
  const __bf16* Bptr = Bt + (size_t)(n0 + r0) * K + kc0;
  const size_t rowstep = (size_t)64 * K;

  for (int k0 = 0; k0 < K; k0 += 32) {
    uint4 a0 = *(const uint4*)(Aptr + k0);
    uint4 a1 = *(const uint4*)(Aptr + rowstep + k0);
    uint4 b0 = *(const uint4*)(Bptr + k0);
    uint4 b1 = *(const uint4*)(Bptr + rowstep + k0);
    __syncthreads();
    *(uint4*)&As[r0 * 40 + kc0] = a0;
    *(uint4*)&As[(r0 + 64) * 40 + kc0] = a1;
    *(uint4*)&Bs[r0 * 40 + kc0] = b0;
    *(uint4*)&Bs[(r0 + 64) * 40 + kc0] = b1;
    __syncthreads();
    bf16x8 af[4], bfv[4];
#pragma unroll
    for (int i = 0; i < 4; i++)
      af[i] = *(const bf16x8*)&As[(wm + i * 16 + l16) * 40 + quad * 8];
#pragma unroll
    for (int j = 0; j < 4; j++)
      bfv[j] = *(const bf16x8*)&Bs[(wn + j * 16 + l16) * 40 + quad * 8];
#pragma unroll
    for (int i = 0; i < 4; i++)
#pragma unroll
      for (int j = 0; j < 4; j++)
        acc[i][j] = __builtin_amdgcn_mfma_f32_16x16x32_bf16(af[i], bfv[j],
                                                            acc[i][j], 0, 0, 0);
  }

#pragma unroll
  for (int i = 0; i < 4; i++)
#pragma unroll
    for (int j = 0; j < 4; j++) {
      const int col = n0 + wn + j * 16 + l16;
      const float bv = bias[col];
#pragma unroll
      for (int r = 0; r < 4; r++) {
        const int row = m0 + wm + i * 16 + quad * 4 + r;
        outF[(size_t)row * Ncols + col] = acc[i][j][r] + bv;
      }
    }
}

extern "C" void kernel_launch(void* const* d_in, const int* in_sizes, int n_in,
                              void* d_out, int out_size, void* d_ws,
                              size_t ws_size, hipStream_t stream) {
  const float* x = (const float*)d_in[0];       // [2,2048,2048]
  const float* w_qkv = (const float*)d_in[1];   // [2048,6144]
  const float* b_qkv = (const float*)d_in[2];   // [6144]
  const float* w_proj = (const float*)d_in[3];  // [2048,2048]
  const float* b_proj = (const float*)d_in[4];  // [2048]
  float* out = (float*)d_out;                   // [2,2048,2048] fp32

  const size_t HSZ = (size_t)16 * 2048 * 256;  // 8M elems = 16 MiB bf16
  __bf16* qh = (__bf16*)d_ws;
  __bf16* ql = qh + HSZ;
  __bf16* kh = ql + HSZ;
  __bf16* kl = kh + HSZ;
  __bf16* vT = kl + HSZ;
  __bf16* attn = vT + HSZ;
  __bf16* wprojT = qh;  // aliases qh/ql region AFTER attention

  gemm_qkv_split_k<<<dim3(48, 32), 256, 0, stream>>>(x, w_qkv, b_qkv, qh, ql,
                                                     kh, kl, vT);
  attn_fwd_k<<<dim3(32, 16), 256, 0, stream>>>(qh, ql, kh, kl, vT, attn);
  transpose_cvt_k<<<dim3(64, 64), 256, 0, stream>>>(w_proj, wprojT, 2048, 2048);
  gemm_bt_k<<<dim3(16, 32), 256, 0, stream>>>(attn, wprojT, b_proj, 4096, 2048,
                                              2048, out);
}

// Round 6
// 1167.517 us; speedup vs baseline: 1.4649x; 1.3420x over previous
//
#include <hip/hip_runtime.h>
#include <cstdint>
#include <cstddef>

// MultiHeadAttention: B=2, N=2048, EMB=2048, H=8, D=256.  fp32 I/O.
// R5: 1567 us, attn = 1010 us, latency-serialized per-wave K/V global loads
// (MfmaUtil 5.4%, VALU 6.7%, HBM 2.9% -- all idle).  R6: cooperative LDS
// staging of K/V tiles (kv-tile 32, 58 KB LDS, 2 blocks/CU), inner loop =
// ds_read_b128 + MFMA only.  K tile stride 264 and V tile stride 32 are both
// bank-even for b128 (8 accesses/bank = floor).
// ws (96 MiB): qh 16 | ql 16 | kh 16 | kl 16 | vT 16 | attn 16 ;
// wprojT aliases qh after attention.

typedef __bf16 bf16x8 __attribute__((ext_vector_type(8)));
typedef __bf16 bf16x2 __attribute__((ext_vector_type(2)));
typedef float f32x4 __attribute__((ext_vector_type(4)));

#define SCALE_INV 0.022097086912079608f  // 1/sqrt(2048)

__device__ inline void split8(const float4 v0, const float4 v1, bf16x8& hi,
                              bf16x8& lo) {
  float a[8] = {v0.x, v0.y, v0.z, v0.w, v1.x, v1.y, v1.z, v1.w};
  bf16x8 h, l;
#pragma unroll
  for (int i = 0; i < 8; i++) {
    __bf16 hh = (__bf16)a[i];
    h[i] = hh;
    l[i] = (__bf16)(a[i] - (float)hh);
  }
  hi = h;
  lo = l;
}

// out[c][r] = (bf16) in[r][c]
__global__ __launch_bounds__(256) void transpose_cvt_k(
    const float* __restrict__ in, __bf16* __restrict__ out, int R, int C) {
  __shared__ float tile[32][33];
  const int tx = threadIdx.x & 31;
  const int ty = threadIdx.x >> 5;
  const int c0 = blockIdx.x * 32;
  const int r0 = blockIdx.y * 32;
#pragma unroll
  for (int i = 0; i < 32; i += 8)
    tile[ty + i][tx] = in[(size_t)(r0 + ty + i) * C + (c0 + tx)];
  __syncthreads();
#pragma unroll
  for (int i = 0; i < 32; i += 8)
    out[(size_t)(c0 + ty + i) * R + (r0 + tx)] = (__bf16)tile[tx][ty + i];
}

// QKV GEMM, split-bf16 3-pass.  A = X fp32 [4096][2048] row-major.
// B = W fp32 [2048][6144] row-major (transposed during LDS staging).
// Scatter: col = h*768 + d*3 + c -> qh/ql, kh/kl (bf16 hi/lo pairs), vT bf16.
__global__ __launch_bounds__(256) void gemm_qkv_split_k(
    const float* __restrict__ X, const float* __restrict__ W,
    const float* __restrict__ bias, __bf16* __restrict__ qh_,
    __bf16* __restrict__ ql_, __bf16* __restrict__ kh_,
    __bf16* __restrict__ kl_, __bf16* __restrict__ vT) {
  __shared__ __bf16 Ah[128 * 40], Al[128 * 40];
  __shared__ __bf16 Bh[128 * 40], Bl[128 * 40];
  const int tid = threadIdx.x, lane = tid & 63, wave = tid >> 6;
  const int l16 = lane & 15, quad = lane >> 4;
  const int wm = (wave >> 1) * 64, wn = (wave & 1) * 64;
  const int m0 = blockIdx.y * 128, n0 = blockIdx.x * 128;
  const int r0 = tid >> 2, kc0 = (tid & 3) * 8;
  const int bn = tid & 31;        // B-staging: base n (coalesced)
  const int bk = (tid >> 5) * 2;  // B-staging: even k in [0,16)

  f32x4 zero4 = {0.f, 0.f, 0.f, 0.f};
  f32x4 acc[4][4];
#pragma unroll
  for (int i = 0; i < 4; i++)
#pragma unroll
    for (int j = 0; j < 4; j++) acc[i][j] = zero4;

  const float* Arow0 = X + (size_t)(m0 + r0) * 2048 + kc0;
  const float* Arow1 = Arow0 + (size_t)64 * 2048;

  for (int k0 = 0; k0 < 2048; k0 += 32) {
    float4 a00 = *(const float4*)(Arow0 + k0);
    float4 a01 = *(const float4*)(Arow0 + k0 + 4);
    float4 a10 = *(const float4*)(Arow1 + k0);
    float4 a11 = *(const float4*)(Arow1 + k0 + 4);
    float wv[2][4][2];
#pragma unroll
    for (int p = 0; p < 2; p++) {
      const int kk = k0 + p * 16 + bk;
#pragma unroll
      for (int i = 0; i < 4; i++) {
        const int nn = n0 + bn + 32 * i;
        wv[p][i][0] = W[(size_t)kk * 6144 + nn];
        wv[p][i][1] = W[(size_t)(kk + 1) * 6144 + nn];
      }
    }
    bf16x8 ah0, al0, ah1, al1;
    split8(a00, a01, ah0, al0);
    split8(a10, a11, ah1, al1);
    __syncthreads();
    *(bf16x8*)&Ah[r0 * 40 + kc0] = ah0;
    *(bf16x8*)&Al[r0 * 40 + kc0] = al0;
    *(bf16x8*)&Ah[(r0 + 64) * 40 + kc0] = ah1;
    *(bf16x8*)&Al[(r0 + 64) * 40 + kc0] = al1;
#pragma unroll
    for (int p = 0; p < 2; p++) {
      const int kk = p * 16 + bk;
#pragma unroll
      for (int i = 0; i < 4; i++) {
        const int nn = bn + 32 * i;
        const float a = wv[p][i][0], b = wv[p][i][1];
        __bf16 h0 = (__bf16)a, h1 = (__bf16)b;
        bf16x2 h = {h0, h1};
        bf16x2 l = {(__bf16)(a - (float)h0), (__bf16)(b - (float)h1)};
        *(bf16x2*)&Bh[nn * 40 + kk] = h;
        *(bf16x2*)&Bl[nn * 40 + kk] = l;
      }
    }
    __syncthreads();
    bf16x8 fah[4], fal[4], fbh[4], fbl[4];
#pragma unroll
    for (int i = 0; i < 4; i++) {
      fah[i] = *(const bf16x8*)&Ah[(wm + i * 16 + l16) * 40 + quad * 8];
      fal[i] = *(const bf16x8*)&Al[(wm + i * 16 + l16) * 40 + quad * 8];
    }
#pragma unroll
    for (int j = 0; j < 4; j++) {
      fbh[j] = *(const bf16x8*)&Bh[(wn + j * 16 + l16) * 40 + quad * 8];
      fbl[j] = *(const bf16x8*)&Bl[(wn + j * 16 + l16) * 40 + quad * 8];
    }
#pragma unroll
    for (int i = 0; i < 4; i++)
#pragma unroll
      for (int j = 0; j < 4; j++) {
        acc[i][j] = __builtin_amdgcn_mfma_f32_16x16x32_bf16(fah[i], fbh[j],
                                                            acc[i][j], 0, 0, 0);
        acc[i][j] = __builtin_amdgcn_mfma_f32_16x16x32_bf16(fah[i], fbl[j],
                                                            acc[i][j], 0, 0, 0);
        acc[i][j] = __builtin_amdgcn_mfma_f32_16x16x32_bf16(fal[i], fbh[j],
                                                            acc[i][j], 0, 0, 0);
      }
  }

#pragma unroll
  for (int i = 0; i < 4; i++) {
#pragma unroll
    for (int j = 0; j < 4; j++) {
      const int col = n0 + wn + j * 16 + l16;
      const float bv = bias[col];
      const int h = col / 768;
      const int rr = col - h * 768;
      const int d = rr / 3;
      const int c = rr - d * 3;
#pragma unroll
      for (int r = 0; r < 4; r++) {
        const int row = m0 + wm + i * 16 + quad * 4 + r;
        const float v = acc[i][j][r] + bv;
        const int b = row >> 11;
        const int nn = row & 2047;
        const int bh = b * 8 + h;
        const size_t idx = ((size_t)bh * 2048 + nn) * 256 + d;
        if (c == 0) {
          __bf16 hi = (__bf16)v;
          qh_[idx] = hi;
          ql_[idx] = (__bf16)(v - (float)hi);
        } else if (c == 1) {
          __bf16 hi = (__bf16)v;
          kh_[idx] = hi;
          kl_[idx] = (__bf16)(v - (float)hi);
        } else {
          vT[((size_t)bh * 256 + d) * 2048 + nn] = (__bf16)v;
        }
      }
    }
  }
}

// Flash attention.  Q/K hi/lo bf16 pairs; cooperative LDS staging of K/V
// tiles (kv-tile = 32).  Inner loop: ds_read_b128 + MFMA only.
#define KSTR 264  // Kh/Kl LDS row stride (elems): bank-even for b128 reads
__global__ __launch_bounds__(256) void attn_fwd_k(
    const __bf16* __restrict__ Qh,  // [16][2048][256]
    const __bf16* __restrict__ Ql,
    const __bf16* __restrict__ Kh,
    const __bf16* __restrict__ Kl,
    const __bf16* __restrict__ Vt,  // [16][256][2048]
    __bf16* __restrict__ out) {     // [2][2048][2048] (b, n, h*256+d)
  __shared__ __bf16 KhL[32 * KSTR];  // 16.9 KB
  __shared__ __bf16 KlL[32 * KSTR];  // 16.9 KB
  __shared__ __bf16 VL[256 * 32];    // 16 KB, stride 32 bank-even for b128
  __shared__ __bf16 Plds[4][16 * 40];  // per-wave, 5 KB

  const int qblk = blockIdx.x;
  const int bh = blockIdx.y;
  const int bb = bh >> 3, hh = bh & 7;
  const int tid = threadIdx.x, lane = tid & 63, wave = tid >> 6;
  const int l16 = lane & 15, quad = lane >> 4;

  const size_t hqk = (size_t)bh * 2048 * 256;
  const __bf16* qhp = Qh + hqk;
  const __bf16* qlp = Ql + hqk;
  const __bf16* khp = Kh + hqk;
  const __bf16* klp = Kl + hqk;
  const __bf16* vp = Vt + (size_t)bh * 256 * 2048;

  const int qrow = qblk * 64 + wave * 16;

  bf16x8 qhf[8], qlf[8];
#pragma unroll
  for (int t = 0; t < 8; t++) {
    const size_t off = (size_t)(qrow + l16) * 256 + t * 32 + quad * 8;
    qhf[t] = *(const bf16x8*)&qhp[off];
    qlf[t] = *(const bf16x8*)&qlp[off];
  }

  f32x4 zero4 = {0.f, 0.f, 0.f, 0.f};
  f32x4 o[16];
#pragma unroll
  for (int dt = 0; dt < 16; dt++) o[dt] = zero4;
  float mrow[4], lrow[4];
#pragma unroll
  for (int r = 0; r < 4; r++) {
    mrow[r] = -3.0e38f;
    lrow[r] = 0.f;
  }

  // staging indices: K tile rows via (sr + i*8), 32B chunks via sc;
  // V tile: one row (=d) per thread.
  const int sr = tid >> 5;  // 0..7
  const int sc = tid & 31;  // 0..31

  for (int kv0 = 0; kv0 < 2048; kv0 += 32) {
    // issue global loads for this tile before the barrier (overlap)
    uint4 kh4[4], kl4[4], v4[4];
#pragma unroll
    for (int i = 0; i < 4; i++) {
      const size_t go = (size_t)(kv0 + sr + i * 8) * 256 + sc * 8;
      kh4[i] = *(const uint4*)&khp[go];
      kl4[i] = *(const uint4*)&klp[go];
      v4[i] = *(const uint4*)&vp[(size_t)tid * 2048 + kv0 + i * 8];
    }
    __syncthreads();  // previous iter's LDS reads done
#pragma unroll
    for (int i = 0; i < 4; i++) {
      *(uint4*)&KhL[(sr + i * 8) * KSTR + sc * 8] = kh4[i];
      *(uint4*)&KlL[(sr + i * 8) * KSTR + sc * 8] = kl4[i];
      *(uint4*)&VL[tid * 32 + i * 8] = v4[i];
    }
    __syncthreads();  // tile visible to all waves

    // S = q_tile @ k_tile^T : 2 tiles of 16x16, split-bf16 3-pass
    f32x4 s[2];
    s[0] = zero4;
    s[1] = zero4;
#pragma unroll
    for (int j = 0; j < 2; j++) {
#pragma unroll
      for (int t = 0; t < 8; t++) {
        bf16x8 khf = *(const bf16x8*)&KhL[(j * 16 + l16) * KSTR + t * 32 + quad * 8];
        bf16x8 klf = *(const bf16x8*)&KlL[(j * 16 + l16) * KSTR + t * 32 + quad * 8];
        s[j] =
            __builtin_amdgcn_mfma_f32_16x16x32_bf16(qhf[t], khf, s[j], 0, 0, 0);
        s[j] =
            __builtin_amdgcn_mfma_f32_16x16x32_bf16(qhf[t], klf, s[j], 0, 0, 0);
        s[j] =
            __builtin_amdgcn_mfma_f32_16x16x32_bf16(qlf[t], khf, s[j], 0, 0, 0);
      }
    }
    // online softmax (rows quad*4+r, cols l16 of 2 kv subtiles)
    float mnew[4], alpha[4], psum[4];
#pragma unroll
    for (int r = 0; r < 4; r++) {
      float mx = fmaxf(s[0][r], s[1][r]);
#pragma unroll
      for (int off = 1; off < 16; off <<= 1)
        mx = fmaxf(mx, __shfl_xor(mx, off, 16));
      mnew[r] = fmaxf(mrow[r], mx);
      alpha[r] = __expf(mrow[r] - mnew[r]);
      psum[r] = 0.f;
    }
#pragma unroll
    for (int j = 0; j < 2; j++)
#pragma unroll
      for (int r = 0; r < 4; r++) {
        float p = __expf(s[j][r] - mnew[r]);
        s[j][r] = p;
        psum[r] += p;
      }
#pragma unroll
    for (int r = 0; r < 4; r++) {
#pragma unroll
      for (int off = 1; off < 16; off <<= 1)
        psum[r] += __shfl_xor(psum[r], off, 16);
      lrow[r] = lrow[r] * alpha[r] + psum[r];
      mrow[r] = mnew[r];
    }
#pragma unroll
    for (int dt = 0; dt < 16; dt++) {
      o[dt][0] *= alpha[0];
      o[dt][1] *= alpha[1];
      o[dt][2] *= alpha[2];
      o[dt][3] *= alpha[3];
    }
    // P: C-layout -> per-wave LDS -> A-operand layout (no barrier: wave-private)
#pragma unroll
    for (int j = 0; j < 2; j++)
#pragma unroll
      for (int r = 0; r < 4; r++)
        Plds[wave][(quad * 4 + r) * 40 + j * 16 + l16] = (__bf16)s[j][r];
    bf16x8 pa = *(const bf16x8*)&Plds[wave][l16 * 40 + quad * 8];
    // O += P @ V
#pragma unroll
    for (int dt = 0; dt < 16; dt++) {
      bf16x8 vf = *(const bf16x8*)&VL[(dt * 16 + l16) * 32 + quad * 8];
      o[dt] = __builtin_amdgcn_mfma_f32_16x16x32_bf16(pa, vf, o[dt], 0, 0, 0);
    }
  }

#pragma unroll
  for (int r = 0; r < 4; r++) {
    const float inv = SCALE_INV / lrow[r];
    const int n = qrow + quad * 4 + r;
    const size_t base = ((size_t)bb * 2048 + n) * 2048 + hh * 256;
#pragma unroll
    for (int dt = 0; dt < 16; dt++)
      out[base + dt * 16 + l16] = (__bf16)(o[dt][r] * inv);
  }
}

// Plain bf16 GEMM, C = A[M][K] * Bt[N][K]^T + bias, fp32 store.
__global__ __launch_bounds__(256) void gemm_bt_k(
    const __bf16* __restrict__ A, const __bf16* __restrict__ Bt,
    const float* __restrict__ bias, int M, int Ncols, int K,
    float* __restrict__ outF) {
  __shared__ __bf16 As[128 * 40];
  __shared__ __bf16 Bs[128 * 40];
  const int tid = threadIdx.x, lane = tid & 63, wave = tid >> 6;
  const int l16 = lane & 15, quad = lane >> 4;
  const int wm = (wave >> 1) * 64, wn = (wave & 1) * 64;
  const int m0 = blockIdx.y * 128, n0 = blockIdx.x * 128;
  const int r0 = tid >> 2, kc0 = (tid & 3) * 8;

  f32x4 zero4 = {0.f, 0.f, 0.f, 0.f};
  f32x4 acc[4][4];
#pragma unroll
  for (int i = 0; i < 4; i++)
#pragma unroll
    for (int j = 0; j < 4; j++) acc[i][j] = zero4;

  const __bf16* Aptr = A + (size_t)(m0 + r0) * K + kc0;
  const __bf16* Bptr = Bt + (size_t)(n0 + r0) * K + kc0;
  const size_t rowstep = (size_t)64 * K;

  for (int k0 = 0; k0 < K; k0 += 32) {
    uint4 a0 = *(const uint4*)(Aptr + k0);
    uint4 a1 = *(const uint4*)(Aptr + rowstep + k0);
    uint4 b0 = *(const uint4*)(Bptr + k0);
    uint4 b1 = *(const uint4*)(Bptr + rowstep + k0);
    __syncthreads();
    *(uint4*)&As[r0 * 40 + kc0] = a0;
    *(uint4*)&As[(r0 + 64) * 40 + kc0] = a1;
    *(uint4*)&Bs[r0 * 40 + kc0] = b0;
    *(uint4*)&Bs[(r0 + 64) * 40 + kc0] = b1;
    __syncthreads();
    bf16x8 af[4], bfv[4];
#pragma unroll
    for (int i = 0; i < 4; i++)
      af[i] = *(const bf16x8*)&As[(wm + i * 16 + l16) * 40 + quad * 8];
#pragma unroll
    for (int j = 0; j < 4; j++)
      bfv[j] = *(const bf16x8*)&Bs[(wn + j * 16 + l16) * 40 + quad * 8];
#pragma unroll
    for (int i = 0; i < 4; i++)
#pragma unroll
      for (int j = 0; j < 4; j++)
        acc[i][j] = __builtin_amdgcn_mfma_f32_16x16x32_bf16(af[i], bfv[j],
                                                            acc[i][j], 0, 0, 0);
  }

#pragma unroll
  for (int i = 0; i < 4; i++)
#pragma unroll
    for (int j = 0; j < 4; j++) {
      const int col = n0 + wn + j * 16 + l16;
      const float bv = bias[col];
#pragma unroll
      for (int r = 0; r < 4; r++) {
        const int row = m0 + wm + i * 16 + quad * 4 + r;
        outF[(size_t)row * Ncols + col] = acc[i][j][r] + bv;
      }
    }
}

extern "C" void kernel_launch(void* const* d_in, const int* in_sizes, int n_in,
                              void* d_out, int out_size, void* d_ws,
                              size_t ws_size, hipStream_t stream) {
  const float* x = (const float*)d_in[0];       // [2,2048,2048]
  const float* w_qkv = (const float*)d_in[1];   // [2048,6144]
  const float* b_qkv = (const float*)d_in[2];   // [6144]
  const float* w_proj = (const float*)d_in[3];  // [2048,2048]
  const float* b_proj = (const float*)d_in[4];  // [2048]
  float* out = (float*)d_out;                   // [2,2048,2048] fp32

  const size_t HSZ = (size_t)16 * 2048 * 256;  // 8M elems = 16 MiB bf16
  __bf16* qh = (__bf16*)d_ws;
  __bf16* ql = qh + HSZ;
  __bf16* kh = ql + HSZ;
  __bf16* kl = kh + HSZ;
  __bf16* vT = kl + HSZ;
  __bf16* attn = vT + HSZ;
  __bf16* wprojT = qh;  // aliases qh/ql region AFTER attention

  gemm_qkv_split_k<<<dim3(48, 32), 256, 0, stream>>>(x, w_qkv, b_qkv, qh, ql,
                                                     kh, kl, vT);
  attn_fwd_k<<<dim3(32, 16), 256, 0, stream>>>(qh, ql, kh, kl, vT, attn);
  transpose_cvt_k<<<dim3(64, 64), 256, 0, stream>>>(w_proj, wprojT, 2048, 2048);
  gemm_bt_k<<<dim3(16, 32), 256, 0, stream>>>(attn, wprojT, b_proj, 4096, 2048,
                                              2048, out);
}